// Round 5
// baseline (1158.618 us; speedup 1.0000x reference)
//
#include <hip/hip_runtime.h>
#include <math.h>

#define H_ENC 128
#define H_DEC 256
#define L_SRC 512
#define T_DEC 96
#define B_TOT 1024

typedef _Float16 half8 __attribute__((ext_vector_type(8)));
typedef float f32x4 __attribute__((ext_vector_type(4)));

#define MFMA16(A, B, C) __builtin_amdgcn_mfma_f32_16x16x32_f16((A), (B), (C), 0, 0, 0)

__device__ __forceinline__ half8 as_h8(uint4 v) { union { uint4 u; half8 h; } x; x.u = v; return x.h; }
__device__ __forceinline__ unsigned packu(float a, float b) {
    union { _Float16 h[2]; unsigned u; } x; x.h[0] = (_Float16)a; x.h[1] = (_Float16)b; return x.u;
}

// division/clamp-free (NaN-safe at +-inf)
__device__ __forceinline__ float sigmoidf_(float x) {
    return __builtin_amdgcn_rcpf(1.f + __expf(-x));
}
__device__ __forceinline__ float tanhf_(float x) {
    return 1.f - 2.f * __builtin_amdgcn_rcpf(__expf(2.f * x) + 1.f);
}

// ---------------- Weight pre-pack (decoder) ----------------
// packW u32 layout: ((n*8 + kt)*64 + l)*4 + q ; lane l holds
// Whh[16n + (l&15)][32kt + 8*(l>>4) + 2q .. +1] as f16 pair.
__global__ void pack_weights(const float* __restrict__ Whh, unsigned* __restrict__ packW) {
    const int n = blockIdx.x;        // 0..63 N-tile
    const int l = threadIdx.x;       // 0..63
    const int row = 16 * n + (l & 15);
    const int g = l >> 4;
    #pragma unroll
    for (int kt = 0; kt < 8; ++kt) {
        const float* p = Whh + (size_t)row * H_DEC + 32 * kt + 8 * g;
        float4 v0 = *reinterpret_cast<const float4*>(p);
        float4 v1 = *reinterpret_cast<const float4*>(p + 4);
        unsigned* q = packW + ((size_t)(n * 8 + kt) * 64 + l) * 4;
        q[0] = packu(v0.x, v0.y); q[1] = packu(v0.z, v0.w);
        q[2] = packu(v1.x, v1.y); q[3] = packu(v1.z, v1.w);
    }
}

// ---------------- Encoder (MFMA, EB=8, 256 blocks) ----------------
// 2 independent chains per SIMD: one block's stall hides under the other's.
// M=8 valid batches in a 16-row tile (rows 8..15 zero-padded).
#define EB 8
#define HPAD 136
__global__ __launch_bounds__(512, 2)
void encoder_mfma(
    const float* __restrict__ source,
    const float* __restrict__ Wih_f, const float* __restrict__ Whh_f, const float* __restrict__ b_f,
    const float* __restrict__ Wih_b, const float* __restrict__ Whh_b, const float* __restrict__ b_b,
    float* __restrict__ h0, float* __restrict__ c0)
{
    const int dir = blockIdx.x & 1;
    const int bg  = blockIdx.x >> 1;       // 0..127
    const int t   = threadIdx.x;
    const int w   = t >> 6;
    const int l   = t & 63;
    const int col = l & 15;
    const int grp = l >> 4;

    const float* Wih = dir ? Wih_b : Wih_f;
    const float* Whh = dir ? Whh_b : Whh_f;
    const float* bb  = dir ? b_b   : b_f;

    __shared__ float    xsT[L_SRC][16];        // rows 8..15 zero
    __shared__ _Float16 hbuf[2][16][HPAD];     // rows 8..15 stay zero

    {
        const float* srcb = source + (size_t)bg * EB * L_SRC;
        for (int i = t; i < EB * L_SRC; i += 512) {
            int b = i >> 9, st = i & 511;
            xsT[st][b] = srcb[i];              // coalesced global read
        }
        for (int i = t; i < EB * L_SRC; i += 512)
            xsT[i & 511][8 + (i >> 9)] = 0.f;
        for (int i = t; i < 2 * 16 * HPAD; i += 512)
            ((_Float16*)hbuf)[i] = (_Float16)0.f;
    }

    const int e = 16 * w + col;                // my h-elem 0..127

    half8 wfrag[16];
    #pragma unroll
    for (int tt = 0; tt < 4; ++tt) {
        const float* wr = Whh + (size_t)(128 * tt + e) * H_ENC;
        #pragma unroll
        for (int kt = 0; kt < 4; ++kt) {
            const float* p = wr + 32 * kt + 8 * grp;
            float4 v0 = *reinterpret_cast<const float4*>(p);
            float4 v1 = *reinterpret_cast<const float4*>(p + 4);
            half8 h;
            h[0] = (_Float16)v0.x; h[1] = (_Float16)v0.y; h[2] = (_Float16)v0.z; h[3] = (_Float16)v0.w;
            h[4] = (_Float16)v1.x; h[5] = (_Float16)v1.y; h[6] = (_Float16)v1.z; h[7] = (_Float16)v1.w;
            wfrag[4 * tt + kt] = h;
        }
    }
    float bias4[4], wih4[4];
    #pragma unroll
    for (int tt = 0; tt < 4; ++tt) { bias4[tt] = bb[128 * tt + e]; wih4[tt] = Wih[128 * tt + e]; }

    float c4[4] = {0.f, 0.f, 0.f, 0.f};
    float hout[4] = {0.f, 0.f, 0.f, 0.f};
    __syncthreads();

    int cur = 0;
    for (int s = 0; s < L_SRC; ++s) {
        const int step = dir ? (L_SRC - 1 - s) : s;

        float4 xv = *reinterpret_cast<const float4*>(&xsT[step][4 * grp]);

        half8 a0 = *reinterpret_cast<const half8*>(&hbuf[cur][col][ 0 + 8 * grp]);
        half8 a1 = *reinterpret_cast<const half8*>(&hbuf[cur][col][32 + 8 * grp]);
        half8 a2 = *reinterpret_cast<const half8*>(&hbuf[cur][col][64 + 8 * grp]);
        half8 a3 = *reinterpret_cast<const half8*>(&hbuf[cur][col][96 + 8 * grp]);

        f32x4 acc0 = {0.f, 0.f, 0.f, 0.f};
        f32x4 acc1 = {0.f, 0.f, 0.f, 0.f};
        f32x4 acc2 = {0.f, 0.f, 0.f, 0.f};
        f32x4 acc3 = {0.f, 0.f, 0.f, 0.f};
        acc0 = MFMA16(a0, wfrag[0],  acc0); acc0 = MFMA16(a1, wfrag[1],  acc0);
        acc0 = MFMA16(a2, wfrag[2],  acc0); acc0 = MFMA16(a3, wfrag[3],  acc0);
        acc1 = MFMA16(a0, wfrag[4],  acc1); acc1 = MFMA16(a1, wfrag[5],  acc1);
        acc1 = MFMA16(a2, wfrag[6],  acc1); acc1 = MFMA16(a3, wfrag[7],  acc1);
        acc2 = MFMA16(a0, wfrag[8],  acc2); acc2 = MFMA16(a1, wfrag[9],  acc2);
        acc2 = MFMA16(a2, wfrag[10], acc2); acc2 = MFMA16(a3, wfrag[11], acc2);
        acc3 = MFMA16(a0, wfrag[12], acc3); acc3 = MFMA16(a1, wfrag[13], acc3);
        acc3 = MFMA16(a2, wfrag[14], acc3); acc3 = MFMA16(a3, wfrag[15], acc3);

        #pragma unroll
        for (int r = 0; r < 4; ++r) {
            float x = (r == 0) ? xv.x : (r == 1) ? xv.y : (r == 2) ? xv.z : xv.w;
            float gi = sigmoidf_(acc0[r] + bias4[0] + wih4[0] * x);
            float gf = sigmoidf_(acc1[r] + bias4[1] + wih4[1] * x);
            float gg = tanhf_  (acc2[r] + bias4[2] + wih4[2] * x);
            float go = sigmoidf_(acc3[r] + bias4[3] + wih4[3] * x);
            c4[r] = gf * c4[r] + gi * gg;
            float h = go * tanhf_(c4[r]);
            hout[r] = h;
            if (grp < 2) hbuf[cur ^ 1][4 * grp + r][e] = (_Float16)h;
        }
        __syncthreads();
        cur ^= 1;
    }

    if (grp < 2) {
        #pragma unroll
        for (int r = 0; r < 4; ++r) {
            size_t b = (size_t)bg * EB + 4 * grp + r;
            h0[b * (2 * H_ENC) + dir * H_ENC + e] = hout[r];
            c0[b * (2 * H_ENC) + dir * H_ENC + e] = c4[r];
        }
    }
}

// ---------------- Decoder (MFMA, L2-streamed packed weights) ----------------
// 64 blocks x 512 thr (8 waves), 16 batches/block. Wave w owns gate-elems
// [32w, 32w+32): tiles n = G*16 + 2w + sg. Weights stream coalesced from
// packW (L2-resident, 512 KB/XCD). h double-buffered f16 in LDS.
#define DPAD 264
__global__ __launch_bounds__(512, 2)
void decoder_mfma(
    const float* __restrict__ Wih,   // [1024,1]
    const float* __restrict__ bb,    // [1024]
    const float* __restrict__ outW,  // [1,256]
    const float* __restrict__ outb,  // [1]
    const float* __restrict__ h0,    // [B,256]
    const float* __restrict__ c0,    // [B,256]
    const unsigned* __restrict__ packW,
    float* __restrict__ out)         // [B,T,1]
{
    const int bg  = blockIdx.x;      // batches [16bg, 16bg+16)
    const int t   = threadIdx.x;
    const int w   = t >> 6;
    const int l   = t & 63;
    const int col = l & 15;
    const int grp = l >> 4;

    __shared__ _Float16 hl[2][16][DPAD];   // 16.9 KB
    __shared__ float    yl[16];
    __shared__ float    owl[H_DEC];
    __shared__ float    ypart[8][16];

    if (t < H_DEC) owl[t] = outW[t];

    const int j0 = 32 * w + col;

    // per-thread gate params for j0, j0+16
    float bI[2], bF[2], bG[2], bO[2], wI[2], wF[2], wG[2], wO[2], ow[2];
    #pragma unroll
    for (int sg = 0; sg < 2; ++sg) {
        int j = j0 + 16 * sg;
        bI[sg] = bb[j];           wI[sg] = Wih[j];
        bF[sg] = bb[256 + j];     wF[sg] = Wih[256 + j];
        bG[sg] = bb[512 + j];     wG[sg] = Wih[512 + j];
        bO[sg] = bb[768 + j];     wO[sg] = Wih[768 + j];
    }
    const float ob = outb[0];

    float c[2][4];
    #pragma unroll
    for (int sg = 0; sg < 2; ++sg)
        #pragma unroll
        for (int r = 0; r < 4; ++r)
            c[sg][r] = c0[(size_t)(bg * 16 + 4 * grp + r) * H_DEC + j0 + 16 * sg];

    for (int i = t; i < 16 * H_DEC; i += 512) {
        int b = i >> 8, j = i & 255;
        hl[0][b][j] = (_Float16)h0[(size_t)(bg * 16 + b) * H_DEC + j];
    }
    if (t < 16) yl[t] = 0.f;
    __syncthreads();

    #pragma unroll
    for (int sg = 0; sg < 2; ++sg) { ow[sg] = owl[j0 + 16 * sg]; }

    int cur = 0;
    for (int s = 0; s < T_DEC; ++s) {
        // A-frags: lane holds h[batch=col][32kt + 8grp .. +8]
        half8 a[8];
        #pragma unroll
        for (int kt = 0; kt < 8; ++kt)
            a[kt] = *reinterpret_cast<const half8*>(&hl[cur][col][32 * kt + 8 * grp]);

        f32x4 acc[4][2];
        #pragma unroll
        for (int G = 0; G < 4; ++G)
            #pragma unroll
            for (int sg = 0; sg < 2; ++sg)
                acc[G][sg] = (f32x4){0.f, 0.f, 0.f, 0.f};

        #pragma unroll
        for (int kt = 0; kt < 8; ++kt) {
            #pragma unroll
            for (int G = 0; G < 4; ++G) {
                #pragma unroll
                for (int sg = 0; sg < 2; ++sg) {
                    const int n = G * 16 + 2 * w + sg;
                    uint4 bv = *reinterpret_cast<const uint4*>(
                        packW + ((size_t)(n * 8 + kt) * 64 + l) * 4);
                    acc[G][sg] = MFMA16(a[kt], as_h8(bv), acc[G][sg]);
                }
            }
        }

        // update: batch b = 4grp + r, elems j0, j0+16
        #pragma unroll
        for (int r = 0; r < 4; ++r) {
            float yb = yl[4 * grp + r];
            float pr = 0.f;
            #pragma unroll
            for (int sg = 0; sg < 2; ++sg) {
                float gi = sigmoidf_(acc[0][sg][r] + bI[sg] + wI[sg] * yb);
                float gf = sigmoidf_(acc[1][sg][r] + bF[sg] + wF[sg] * yb);
                float gg = tanhf_  (acc[2][sg][r] + bG[sg] + wG[sg] * yb);
                float go = sigmoidf_(acc[3][sg][r] + bO[sg] + wO[sg] * yb);
                float cn = gf * c[sg][r] + gi * gg;
                c[sg][r] = cn;
                float h = go * tanhf_(cn);
                hl[cur ^ 1][4 * grp + r][j0 + 16 * sg] = (_Float16)h;
                pr += h * ow[sg];
            }
            #pragma unroll
            for (int m = 1; m < 16; m <<= 1) pr += __shfl_xor(pr, m);
            if (col == 0) ypart[w][4 * grp + r] = pr;
        }
        __syncthreads();   // h(buf^1) + ypart visible

        if (t < 16) {
            float y = ypart[0][t] + ypart[1][t] + ypart[2][t] + ypart[3][t]
                    + ypart[4][t] + ypart[5][t] + ypart[6][t] + ypart[7][t] + ob;
            yl[t] = y;
            out[(size_t)(bg * 16 + t) * T_DEC + s] = y;
        }
        __syncthreads();   // yl visible
        cur ^= 1;
    }
}

extern "C" void kernel_launch(void* const* d_in, const int* in_sizes, int n_in,
                              void* d_out, int out_size, void* d_ws, size_t ws_size,
                              hipStream_t stream) {
    const float* source = (const float*)d_in[0];
    const float* eWih_f = (const float*)d_in[2];
    const float* eWhh_f = (const float*)d_in[3];
    const float* eb_f   = (const float*)d_in[4];
    const float* eWih_b = (const float*)d_in[5];
    const float* eWhh_b = (const float*)d_in[6];
    const float* eb_b   = (const float*)d_in[7];
    const float* dWih   = (const float*)d_in[8];
    const float* dWhh   = (const float*)d_in[9];
    const float* db     = (const float*)d_in[10];
    const float* oW     = (const float*)d_in[11];
    const float* obp    = (const float*)d_in[12];
    float* out = (float*)d_out;

    float*    h0    = (float*)d_ws;                        // 1024*256 f32
    float*    c0    = h0 + (size_t)B_TOT * H_DEC;          // 1024*256 f32
    unsigned* packW = (unsigned*)(c0 + (size_t)B_TOT * H_DEC);  // 128K u32

    pack_weights<<<64, 64, 0, stream>>>(dWhh, packW);
    encoder_mfma<<<128 * 2, 512, 0, stream>>>(
        source, eWih_f, eWhh_f, eb_f, eWih_b, eWhh_b, eb_b, h0, c0);
    decoder_mfma<<<64, 512, 0, stream>>>(
        dWih, db, oW, obp, h0, c0, packW, out);
}

// Round 6
// 967.155 us; speedup vs baseline: 1.1980x; 1.1980x over previous
//
#include <hip/hip_runtime.h>
#include <math.h>

#define H_ENC 128
#define H_DEC 256
#define L_SRC 512
#define T_DEC 96
#define B_TOT 1024

typedef _Float16 half8 __attribute__((ext_vector_type(8)));
typedef float f32x4 __attribute__((ext_vector_type(4)));

#define MFMA16(A, B, C) __builtin_amdgcn_mfma_f32_16x16x32_f16((A), (B), (C), 0, 0, 0)

__device__ __forceinline__ unsigned packu(float a, float b) {
    union { _Float16 h[2]; unsigned u; } x; x.h[0] = (_Float16)a; x.h[1] = (_Float16)b; return x.u;
}

// division/clamp-free (NaN-safe at +-inf)
__device__ __forceinline__ float sigmoidf_(float x) {
    return __builtin_amdgcn_rcpf(1.f + __expf(-x));
}
__device__ __forceinline__ float tanhf_(float x) {
    return 1.f - 2.f * __builtin_amdgcn_rcpf(__expf(2.f * x) + 1.f);
}

// ---------------- flag init (fresh every launch: graph-replay safe) ----------------
#define CNT_STRIDE 104
__global__ void zero_cnt(int* cnt) {
    int i = blockIdx.x * blockDim.x + threadIdx.x;
    if (i < 64 * CNT_STRIDE) cnt[i] = 0;
}

// ---------------- Encoder (MFMA, EB=8, 256 blocks) — unchanged from R5 ----------------
#define EB 8
#define HPAD 136
__global__ __launch_bounds__(512, 2)
void encoder_mfma(
    const float* __restrict__ source,
    const float* __restrict__ Wih_f, const float* __restrict__ Whh_f, const float* __restrict__ b_f,
    const float* __restrict__ Wih_b, const float* __restrict__ Whh_b, const float* __restrict__ b_b,
    float* __restrict__ h0, float* __restrict__ c0)
{
    const int dir = blockIdx.x & 1;
    const int bg  = blockIdx.x >> 1;
    const int t   = threadIdx.x;
    const int w   = t >> 6;
    const int l   = t & 63;
    const int col = l & 15;
    const int grp = l >> 4;

    const float* Wih = dir ? Wih_b : Wih_f;
    const float* Whh = dir ? Whh_b : Whh_f;
    const float* bb  = dir ? b_b   : b_f;

    __shared__ float    xsT[L_SRC][16];
    __shared__ _Float16 hbuf[2][16][HPAD];

    {
        const float* srcb = source + (size_t)bg * EB * L_SRC;
        for (int i = t; i < EB * L_SRC; i += 512) {
            int b = i >> 9, st = i & 511;
            xsT[st][b] = srcb[i];
        }
        for (int i = t; i < EB * L_SRC; i += 512)
            xsT[i & 511][8 + (i >> 9)] = 0.f;
        for (int i = t; i < 2 * 16 * HPAD; i += 512)
            ((_Float16*)hbuf)[i] = (_Float16)0.f;
    }

    const int e = 16 * w + col;

    half8 wfrag[16];
    #pragma unroll
    for (int tt = 0; tt < 4; ++tt) {
        const float* wr = Whh + (size_t)(128 * tt + e) * H_ENC;
        #pragma unroll
        for (int kt = 0; kt < 4; ++kt) {
            const float* p = wr + 32 * kt + 8 * grp;
            float4 v0 = *reinterpret_cast<const float4*>(p);
            float4 v1 = *reinterpret_cast<const float4*>(p + 4);
            half8 h;
            h[0] = (_Float16)v0.x; h[1] = (_Float16)v0.y; h[2] = (_Float16)v0.z; h[3] = (_Float16)v0.w;
            h[4] = (_Float16)v1.x; h[5] = (_Float16)v1.y; h[6] = (_Float16)v1.z; h[7] = (_Float16)v1.w;
            wfrag[4 * tt + kt] = h;
        }
    }
    float bias4[4], wih4[4];
    #pragma unroll
    for (int tt = 0; tt < 4; ++tt) { bias4[tt] = bb[128 * tt + e]; wih4[tt] = Wih[128 * tt + e]; }

    float c4[4] = {0.f, 0.f, 0.f, 0.f};
    float hout[4] = {0.f, 0.f, 0.f, 0.f};
    __syncthreads();

    int cur = 0;
    for (int s = 0; s < L_SRC; ++s) {
        const int step = dir ? (L_SRC - 1 - s) : s;

        float4 xv = *reinterpret_cast<const float4*>(&xsT[step][4 * grp]);

        half8 a0 = *reinterpret_cast<const half8*>(&hbuf[cur][col][ 0 + 8 * grp]);
        half8 a1 = *reinterpret_cast<const half8*>(&hbuf[cur][col][32 + 8 * grp]);
        half8 a2 = *reinterpret_cast<const half8*>(&hbuf[cur][col][64 + 8 * grp]);
        half8 a3 = *reinterpret_cast<const half8*>(&hbuf[cur][col][96 + 8 * grp]);

        f32x4 acc0 = {0.f, 0.f, 0.f, 0.f};
        f32x4 acc1 = {0.f, 0.f, 0.f, 0.f};
        f32x4 acc2 = {0.f, 0.f, 0.f, 0.f};
        f32x4 acc3 = {0.f, 0.f, 0.f, 0.f};
        acc0 = MFMA16(a0, wfrag[0],  acc0); acc0 = MFMA16(a1, wfrag[1],  acc0);
        acc0 = MFMA16(a2, wfrag[2],  acc0); acc0 = MFMA16(a3, wfrag[3],  acc0);
        acc1 = MFMA16(a0, wfrag[4],  acc1); acc1 = MFMA16(a1, wfrag[5],  acc1);
        acc1 = MFMA16(a2, wfrag[6],  acc1); acc1 = MFMA16(a3, wfrag[7],  acc1);
        acc2 = MFMA16(a0, wfrag[8],  acc2); acc2 = MFMA16(a1, wfrag[9],  acc2);
        acc2 = MFMA16(a2, wfrag[10], acc2); acc2 = MFMA16(a3, wfrag[11], acc2);
        acc3 = MFMA16(a0, wfrag[12], acc3); acc3 = MFMA16(a1, wfrag[13], acc3);
        acc3 = MFMA16(a2, wfrag[14], acc3); acc3 = MFMA16(a3, wfrag[15], acc3);

        #pragma unroll
        for (int r = 0; r < 4; ++r) {
            float x = (r == 0) ? xv.x : (r == 1) ? xv.y : (r == 2) ? xv.z : xv.w;
            float gi = sigmoidf_(acc0[r] + bias4[0] + wih4[0] * x);
            float gf = sigmoidf_(acc1[r] + bias4[1] + wih4[1] * x);
            float gg = tanhf_  (acc2[r] + bias4[2] + wih4[2] * x);
            float go = sigmoidf_(acc3[r] + bias4[3] + wih4[3] * x);
            c4[r] = gf * c4[r] + gi * gg;
            float h = go * tanhf_(c4[r]);
            hout[r] = h;
            if (grp < 2) hbuf[cur ^ 1][4 * grp + r][e] = (_Float16)h;
        }
        __syncthreads();
        cur ^= 1;
    }

    if (grp < 2) {
        #pragma unroll
        for (int r = 0; r < 4; ++r) {
            size_t b = (size_t)bg * EB + 4 * grp + r;
            h0[b * (2 * H_ENC) + dir * H_ENC + e] = hout[r];
            c0[b * (2 * H_ENC) + dir * H_ENC + e] = c4[r];
        }
    }
}

// ---------------- Decoder v2: gate-split, weights in VGPRs, flag-synced ----------------
// 256 blocks = 64 batch-groups x 4 chunks. Block (bg,q): batches [16bg,16bg+16),
// h-elems [64q, 64q+64) = gate rows {j, 256+j, 512+j, 768+j}. Per wave:
// 2 N-tiles x 8 K-tiles = 16 half8 weight frags (64 VGPRs, encoder-proven).
// Siblings exchange h-chunks via LLC (device-scope atomics) + per-step flag barrier.
#define DB 16
__global__ __launch_bounds__(512, 2)
void decoder_split(
    const float* __restrict__ Wih,   // [1024]
    const float* __restrict__ bb,    // [1024]
    const float* __restrict__ outW,  // [256]
    const float* __restrict__ outb,  // [1]
    const float* __restrict__ h0,    // [B,256]
    const float* __restrict__ c0,    // [B,256]
    const float* __restrict__ Whh,   // [1024,256]
    unsigned* __restrict__ hx,       // [2][1024][128] u32 (f16 pairs)
    int* __restrict__ cnt,           // [64][CNT_STRIDE]
    float* __restrict__ out)         // [B,T]
{
    const int blk = blockIdx.x;
    const int bg  = blk & 63;        // siblings at stride 64 -> same XCD slot
    const int q   = blk >> 6;        // chunk 0..3
    const int t   = threadIdx.x;
    const int w   = t >> 6;
    const int l   = t & 63;
    const int col = l & 15;
    const int grp = l >> 4;
    const int u   = w >> 1;          // elem range u: [16u,16u+16) within chunk
    const int fo  = w & 1;           // 0: gates (i,g)   1: gates (f,o)

    __shared__ unsigned hlU[DB][132];        // h^(s-1) f16 pairs, stride 528 B
    __shared__ float    exch[4][2][DB][16];  // [u][f|o][batch][col], bias added
    __shared__ unsigned hnewU[DB][32];       // my chunk's new h, packed
    __shared__ float    yl[DB];
    __shared__ float    owl[H_DEC];
    int* mycnt = cnt + bg * CNT_STRIDE;

    if (t < H_DEC) owl[t] = outW[t];

    const int j0 = 64 * q + 16 * u + col;    // my lane's global h-elem
    const int rA = (fo ? 256 : 0) + j0;      // i | f
    const int rB = (fo ? 768 : 512) + j0;    // o | g ... careful: fo=0 -> g(512), fo=1 -> o(768)

    // weight frags (one-time, f32 -> f16)
    half8 wfA[8], wfB[8];
    #pragma unroll
    for (int kt = 0; kt < 8; ++kt) {
        const float* pa = Whh + (size_t)rA * H_DEC + 32 * kt + 8 * grp;
        const float* pb = Whh + (size_t)rB * H_DEC + 32 * kt + 8 * grp;
        float4 a0 = *reinterpret_cast<const float4*>(pa);
        float4 a1 = *reinterpret_cast<const float4*>(pa + 4);
        float4 b0 = *reinterpret_cast<const float4*>(pb);
        float4 b1 = *reinterpret_cast<const float4*>(pb + 4);
        half8 ha, hb;
        ha[0]=(_Float16)a0.x; ha[1]=(_Float16)a0.y; ha[2]=(_Float16)a0.z; ha[3]=(_Float16)a0.w;
        ha[4]=(_Float16)a1.x; ha[5]=(_Float16)a1.y; ha[6]=(_Float16)a1.z; ha[7]=(_Float16)a1.w;
        hb[0]=(_Float16)b0.x; hb[1]=(_Float16)b0.y; hb[2]=(_Float16)b0.z; hb[3]=(_Float16)b0.w;
        hb[4]=(_Float16)b1.x; hb[5]=(_Float16)b1.y; hb[6]=(_Float16)b1.z; hb[7]=(_Float16)b1.w;
        wfA[kt] = ha; wfB[kt] = hb;
    }

    // per-lane gate params for elem j0
    const float bI = bb[j0],       wI = Wih[j0];
    const float bF = bb[256 + j0], wF = Wih[256 + j0];
    const float bG = bb[512 + j0], wG = Wih[512 + j0];
    const float bO = bb[768 + j0], wO = Wih[768 + j0];
    const float ob = outb[0];

    // c state (even waves own the update for elems 16u+col)
    float c[4];
    #pragma unroll
    for (int r = 0; r < 4; ++r)
        c[r] = c0[(size_t)(bg * DB + 4 * grp + r) * H_DEC + j0];

    // prologue: write my chunk of h^(0) to hx[0], flag step 0
    {
        int batch = t >> 5, pair = t & 31;
        int e = 64 * q + 2 * pair;
        const float* hp = h0 + (size_t)(bg * DB + batch) * H_DEC + e;
        unsigned v = packu(hp[0], hp[1]);
        __hip_atomic_store(&hx[(size_t)(bg * DB + batch) * 128 + 32 * q + pair], v,
                           __ATOMIC_RELAXED, __HIP_MEMORY_SCOPE_AGENT);
    }
    __syncthreads();
    if (t == 0) {
        __hip_atomic_fetch_add(&mycnt[0], 1, __ATOMIC_RELEASE, __HIP_MEMORY_SCOPE_AGENT);
        while (__hip_atomic_load(&mycnt[0], __ATOMIC_RELAXED, __HIP_MEMORY_SCOPE_AGENT) < 4) {}
    }
    __syncthreads();

    for (int s = 1; s <= T_DEC; ++s) {
        const int rb = (s - 1) & 1, wb = s & 1;
        // load full h^(s-1) (all 4 chunks) from LLC into LDS
        #pragma unroll
        for (int i = 0; i < 4; ++i) {
            int j = t + 512 * i;
            int batch = j >> 7, within = j & 127;
            unsigned v = __hip_atomic_load(
                &hx[(size_t)rb * (B_TOT * 128) + (size_t)(bg * DB + batch) * 128 + within],
                __ATOMIC_RELAXED, __HIP_MEMORY_SCOPE_AGENT);
            hlU[batch][within] = v;
        }
        __syncthreads();

        // y^(s-1) = h^(s-1) @ outW + ob (s==1: exactly 0); also out[s-2]
        {
            int batch = t >> 5, seg = t & 31;
            half8 hv = *reinterpret_cast<const half8*>(
                reinterpret_cast<const char*>(hlU) + batch * 528 + seg * 16);
            float sum = 0.f;
            #pragma unroll
            for (int j = 0; j < 8; ++j) sum += (float)hv[j] * owl[8 * seg + j];
            #pragma unroll
            for (int m = 1; m < 32; m <<= 1) sum += __shfl_xor(sum, m);
            if (seg == 0) {
                float yv = sum + ob;
                yl[batch] = (s == 1) ? 0.f : yv;
                if (q == 0 && s >= 2) out[(size_t)(bg * DB + batch) * T_DEC + (s - 2)] = yv;
            }
        }

        // A-frags + MFMA
        half8 a[8];
        #pragma unroll
        for (int kt = 0; kt < 8; ++kt)
            a[kt] = *reinterpret_cast<const half8*>(
                reinterpret_cast<const char*>(hlU) + col * 528 + (32 * kt + 8 * grp) * 2);

        f32x4 accA = {0.f, 0.f, 0.f, 0.f};
        f32x4 accB = {0.f, 0.f, 0.f, 0.f};
        #pragma unroll
        for (int kt = 0; kt < 8; ++kt) {
            accA = MFMA16(a[kt], wfA[kt], accA);
            accB = MFMA16(a[kt], wfB[kt], accB);
        }

        if (fo) {   // odd waves: hand raw f,o gates (with bias) to even waves
            #pragma unroll
            for (int r = 0; r < 4; ++r) {
                exch[u][0][4 * grp + r][col] = accA[r] + bF;   // f
                exch[u][1][4 * grp + r][col] = accB[r] + bO;   // o
            }
        }
        __syncthreads();   // exch + yl visible; hlU reads done

        if (!fo) {  // even waves: full update for (batch 4grp+r, elem j0)
            #pragma unroll
            for (int r = 0; r < 4; ++r) {
                float yb = yl[4 * grp + r];
                float gi = sigmoidf_(accA[r] + bI + wI * yb);
                float gg = tanhf_  (accB[r] + bG + wG * yb);
                float gf = sigmoidf_(exch[u][0][4 * grp + r][col] + wF * yb);
                float go = sigmoidf_(exch[u][1][4 * grp + r][col] + wO * yb);
                c[r] = gf * c[r] + gi * gg;
                float h = go * tanhf_(c[r]);
                reinterpret_cast<_Float16*>(hnewU)[(4 * grp + r) * 64 + 16 * u + col] = (_Float16)h;
            }
        }
        __syncthreads();   // hnewU complete

        // publish my chunk of h^(s)
        {
            int batch = t >> 5, pair = t & 31;
            __hip_atomic_store(
                &hx[(size_t)wb * (B_TOT * 128) + (size_t)(bg * DB + batch) * 128 + 32 * q + pair],
                hnewU[batch][pair], __ATOMIC_RELAXED, __HIP_MEMORY_SCOPE_AGENT);
        }
        __syncthreads();   // drains vmcnt: stores complete before flag
        if (t == 0) {
            __hip_atomic_fetch_add(&mycnt[s], 1, __ATOMIC_RELEASE, __HIP_MEMORY_SCOPE_AGENT);
            while (__hip_atomic_load(&mycnt[s], __ATOMIC_RELAXED, __HIP_MEMORY_SCOPE_AGENT) < 4) {}
        }
        __syncthreads();
    }

    // epilogue: out[95] = y^(96) from hx[0] (h^(96))
    {
        #pragma unroll
        for (int i = 0; i < 4; ++i) {
            int j = t + 512 * i;
            int batch = j >> 7, within = j & 127;
            unsigned v = __hip_atomic_load(
                &hx[(size_t)(bg * DB + batch) * 128 + within],
                __ATOMIC_RELAXED, __HIP_MEMORY_SCOPE_AGENT);
            hlU[batch][within] = v;
        }
        __syncthreads();
        int batch = t >> 5, seg = t & 31;
        half8 hv = *reinterpret_cast<const half8*>(
            reinterpret_cast<const char*>(hlU) + batch * 528 + seg * 16);
        float sum = 0.f;
        #pragma unroll
        for (int j = 0; j < 8; ++j) sum += (float)hv[j] * owl[8 * seg + j];
        #pragma unroll
        for (int m = 1; m < 32; m <<= 1) sum += __shfl_xor(sum, m);
        if (q == 0 && seg == 0)
            out[(size_t)(bg * DB + batch) * T_DEC + (T_DEC - 1)] = sum + ob;
    }
}

extern "C" void kernel_launch(void* const* d_in, const int* in_sizes, int n_in,
                              void* d_out, int out_size, void* d_ws, size_t ws_size,
                              hipStream_t stream) {
    const float* source = (const float*)d_in[0];
    const float* eWih_f = (const float*)d_in[2];
    const float* eWhh_f = (const float*)d_in[3];
    const float* eb_f   = (const float*)d_in[4];
    const float* eWih_b = (const float*)d_in[5];
    const float* eWhh_b = (const float*)d_in[6];
    const float* eb_b   = (const float*)d_in[7];
    const float* dWih   = (const float*)d_in[8];
    const float* dWhh   = (const float*)d_in[9];
    const float* db     = (const float*)d_in[10];
    const float* oW     = (const float*)d_in[11];
    const float* obp    = (const float*)d_in[12];
    float* out = (float*)d_out;

    float*    h0  = (float*)d_ws;                       // 1 MB
    float*    c0  = h0 + (size_t)B_TOT * H_DEC;         // 1 MB
    unsigned* hx  = (unsigned*)(c0 + (size_t)B_TOT * H_DEC);  // 2*1024*128 u32 = 1 MB
    int*      cnt = (int*)(hx + (size_t)2 * B_TOT * 128);     // 64*104 ints

    zero_cnt<<<(64 * CNT_STRIDE + 255) / 256, 256, 0, stream>>>(cnt);
    encoder_mfma<<<128 * 2, 512, 0, stream>>>(
        source, eWih_f, eWhh_f, eb_f, eWih_b, eWhh_b, eb_b, h0, c0);
    decoder_split<<<256, 512, 0, stream>>>(
        dWih, db, oW, obp, h0, c0, dWhh, hx, cnt, out);
}

// Round 7
// 914.959 us; speedup vs baseline: 1.2663x; 1.0570x over previous
//
#include <hip/hip_runtime.h>
#include <math.h>

#define H_ENC 128
#define H_DEC 256
#define L_SRC 512
#define T_DEC 96
#define B_TOT 1024

typedef _Float16 half8 __attribute__((ext_vector_type(8)));
typedef float f32x4 __attribute__((ext_vector_type(4)));

#define MFMA16(A, B, C) __builtin_amdgcn_mfma_f32_16x16x32_f16((A), (B), (C), 0, 0, 0)

__device__ __forceinline__ unsigned packu(float a, float b) {
    union { _Float16 h[2]; unsigned u; } x; x.h[0] = (_Float16)a; x.h[1] = (_Float16)b; return x.u;
}

// division/clamp-free (NaN-safe at +-inf)
__device__ __forceinline__ float sigmoidf_(float x) {
    return __builtin_amdgcn_rcpf(1.f + __expf(-x));
}
__device__ __forceinline__ float tanhf_(float x) {
    return 1.f - 2.f * __builtin_amdgcn_rcpf(__expf(2.f * x) + 1.f);
}

// ---------------- flag init (fresh every launch: graph-replay safe) ----------------
#define CNT_STRIDE 104
__global__ void zero_cnt(int* cnt) {
    int i = blockIdx.x * blockDim.x + threadIdx.x;
    if (i < 64 * CNT_STRIDE) cnt[i] = 0;
}

// ---------------- Encoder v3: 1024 threads, gbuf-redistributed update ----------------
// EB=8 batches/block, grid = 128*2 = 256 blocks (1/CU, 16 waves).
// Wave w owns N-tiles {2w, 2w+1} (32 tiles = 512 gate rows). Update phase is
// redistributed via gbuf so each of the 1024 lanes does exactly ONE
// (batch,elem) LSTM update per step (10 trans) -- no padding-row waste.
#define EB 8
#define HPAD 136
__global__ __launch_bounds__(1024)
void encoder_big(
    const float* __restrict__ source,
    const float* __restrict__ Wih_f, const float* __restrict__ Whh_f, const float* __restrict__ b_f,
    const float* __restrict__ Wih_b, const float* __restrict__ Whh_b, const float* __restrict__ b_b,
    float* __restrict__ h0, float* __restrict__ c0)
{
    const int dir = blockIdx.x & 1;
    const int bg  = blockIdx.x >> 1;       // 0..127
    const int t   = threadIdx.x;           // 0..1023
    const int w   = t >> 6;                // wave 0..15
    const int l   = t & 63;
    const int col = l & 15;
    const int grp = l >> 4;

    const float* Wih = dir ? Wih_b : Wih_f;
    const float* Whh = dir ? Whh_b : Whh_f;
    const float* bb  = dir ? b_b   : b_f;

    __shared__ float    xsT[L_SRC][EB];        // [step][batch] 16 KB
    __shared__ _Float16 hbuf[2][16][HPAD];     // 8.5 KB (rows 8..15 stay zero)
    __shared__ float    gbuf[4][EB][H_ENC];    // 16 KB raw gates

    {
        const float* srcb = source + (size_t)bg * EB * L_SRC;
        for (int i = t; i < EB * L_SRC; i += 1024) {
            int b = i >> 9, st = i & 511;
            xsT[st][b] = srcb[i];              // coalesced read, transposed store
        }
        for (int i = t; i < 2 * 16 * HPAD; i += 1024)
            ((_Float16*)hbuf)[i] = (_Float16)0.f;
    }

    // B-frags for my 2 tiles (gate rows n*16+col), f32 -> f16 once
    half8 wf[2][4];
    #pragma unroll
    for (int tau = 0; tau < 2; ++tau) {
        const int n = 2 * w + tau;
        const int grow = (n >> 3) * H_ENC + 16 * (n & 7) + col;
        const float* wr = Whh + (size_t)grow * H_ENC;
        #pragma unroll
        for (int kt = 0; kt < 4; ++kt) {
            const float* p = wr + 32 * kt + 8 * grp;
            float4 v0 = *reinterpret_cast<const float4*>(p);
            float4 v1 = *reinterpret_cast<const float4*>(p + 4);
            half8 h;
            h[0] = (_Float16)v0.x; h[1] = (_Float16)v0.y; h[2] = (_Float16)v0.z; h[3] = (_Float16)v0.w;
            h[4] = (_Float16)v1.x; h[5] = (_Float16)v1.y; h[6] = (_Float16)v1.z; h[7] = (_Float16)v1.w;
            wf[tau][kt] = h;
        }
    }

    // phase-3 identity: one (batch, elem) per lane
    const int ub = t >> 7;                 // batch 0..7
    const int ue = t & 127;                // h-elem 0..127
    const float bI = bb[ue],           wI = Wih[ue];
    const float bF = bb[H_ENC + ue],   wF = Wih[H_ENC + ue];
    const float bG = bb[2*H_ENC + ue], wG = Wih[2*H_ENC + ue];
    const float bO = bb[3*H_ENC + ue], wO = Wih[3*H_ENC + ue];

    float c = 0.f, hlast = 0.f;
    __syncthreads();

    int cur = 0;
    for (int s = 0; s < L_SRC; ++s) {
        const int step = dir ? (L_SRC - 1 - s) : s;

        // ---- phase 1: MFMA ----
        half8 a0 = *reinterpret_cast<const half8*>(&hbuf[cur][col][ 0 + 8 * grp]);
        half8 a1 = *reinterpret_cast<const half8*>(&hbuf[cur][col][32 + 8 * grp]);
        half8 a2 = *reinterpret_cast<const half8*>(&hbuf[cur][col][64 + 8 * grp]);
        half8 a3 = *reinterpret_cast<const half8*>(&hbuf[cur][col][96 + 8 * grp]);

        f32x4 acc0 = {0.f, 0.f, 0.f, 0.f};
        f32x4 acc1 = {0.f, 0.f, 0.f, 0.f};
        acc0 = MFMA16(a0, wf[0][0], acc0); acc0 = MFMA16(a1, wf[0][1], acc0);
        acc0 = MFMA16(a2, wf[0][2], acc0); acc0 = MFMA16(a3, wf[0][3], acc0);
        acc1 = MFMA16(a0, wf[1][0], acc1); acc1 = MFMA16(a1, wf[1][1], acc1);
        acc1 = MFMA16(a2, wf[1][2], acc1); acc1 = MFMA16(a3, wf[1][3], acc1);

        // ---- phase 2: valid C rows -> gbuf ----
        if (grp < 2) {
            #pragma unroll
            for (int tau = 0; tau < 2; ++tau) {
                const int n = 2 * w + tau;
                const int G = n >> 3;
                const int e = 16 * (n & 7) + col;
                const f32x4 acc = tau ? acc1 : acc0;
                #pragma unroll
                for (int r = 0; r < 4; ++r)
                    gbuf[G][4 * grp + r][e] = acc[r];
            }
        }
        __syncthreads();

        // ---- phase 3: one LSTM update per lane ----
        {
            float x = xsT[step][ub];
            float gi = sigmoidf_(gbuf[0][ub][ue] + bI + wI * x);
            float gf = sigmoidf_(gbuf[1][ub][ue] + bF + wF * x);
            float gg = tanhf_  (gbuf[2][ub][ue] + bG + wG * x);
            float go = sigmoidf_(gbuf[3][ub][ue] + bO + wO * x);
            c = gf * c + gi * gg;
            float h = go * tanhf_(c);
            hlast = h;
            hbuf[cur ^ 1][ub][ue] = (_Float16)h;
        }
        __syncthreads();
        cur ^= 1;
    }

    h0[(size_t)(bg * EB + ub) * (2 * H_ENC) + dir * H_ENC + ue] = hlast;
    c0[(size_t)(bg * EB + ub) * (2 * H_ENC) + dir * H_ENC + ue] = c;
}

// ---------------- Decoder v2 (unchanged from R6, verified) ----------------
#define DB 16
__global__ __launch_bounds__(512, 2)
void decoder_split(
    const float* __restrict__ Wih,   // [1024]
    const float* __restrict__ bb,    // [1024]
    const float* __restrict__ outW,  // [256]
    const float* __restrict__ outb,  // [1]
    const float* __restrict__ h0,    // [B,256]
    const float* __restrict__ c0,    // [B,256]
    const float* __restrict__ Whh,   // [1024,256]
    unsigned* __restrict__ hx,       // [2][1024][128] u32 (f16 pairs)
    int* __restrict__ cnt,           // [64][CNT_STRIDE]
    float* __restrict__ out)         // [B,T]
{
    const int blk = blockIdx.x;
    const int bg  = blk & 63;
    const int q   = blk >> 6;
    const int t   = threadIdx.x;
    const int w   = t >> 6;
    const int l   = t & 63;
    const int col = l & 15;
    const int grp = l >> 4;
    const int u   = w >> 1;
    const int fo  = w & 1;

    __shared__ unsigned hlU[DB][132];
    __shared__ float    exch[4][2][DB][16];
    __shared__ unsigned hnewU[DB][32];
    __shared__ float    yl[DB];
    __shared__ float    owl[H_DEC];
    int* mycnt = cnt + bg * CNT_STRIDE;

    if (t < H_DEC) owl[t] = outW[t];

    const int j0 = 64 * q + 16 * u + col;
    const int rA = (fo ? 256 : 0) + j0;
    const int rB = (fo ? 768 : 512) + j0;

    half8 wfA[8], wfB[8];
    #pragma unroll
    for (int kt = 0; kt < 8; ++kt) {
        const float* pa = Whh + (size_t)rA * H_DEC + 32 * kt + 8 * grp;
        const float* pb = Whh + (size_t)rB * H_DEC + 32 * kt + 8 * grp;
        float4 a0 = *reinterpret_cast<const float4*>(pa);
        float4 a1 = *reinterpret_cast<const float4*>(pa + 4);
        float4 b0 = *reinterpret_cast<const float4*>(pb);
        float4 b1 = *reinterpret_cast<const float4*>(pb + 4);
        half8 ha, hb;
        ha[0]=(_Float16)a0.x; ha[1]=(_Float16)a0.y; ha[2]=(_Float16)a0.z; ha[3]=(_Float16)a0.w;
        ha[4]=(_Float16)a1.x; ha[5]=(_Float16)a1.y; ha[6]=(_Float16)a1.z; ha[7]=(_Float16)a1.w;
        hb[0]=(_Float16)b0.x; hb[1]=(_Float16)b0.y; hb[2]=(_Float16)b0.z; hb[3]=(_Float16)b0.w;
        hb[4]=(_Float16)b1.x; hb[5]=(_Float16)b1.y; hb[6]=(_Float16)b1.z; hb[7]=(_Float16)b1.w;
        wfA[kt] = ha; wfB[kt] = hb;
    }

    const float bI = bb[j0],       wI = Wih[j0];
    const float bF = bb[256 + j0], wF = Wih[256 + j0];
    const float bG = bb[512 + j0], wG = Wih[512 + j0];
    const float bO = bb[768 + j0], wO = Wih[768 + j0];
    const float ob = outb[0];

    float c[4];
    #pragma unroll
    for (int r = 0; r < 4; ++r)
        c[r] = c0[(size_t)(bg * DB + 4 * grp + r) * H_DEC + j0];

    {
        int batch = t >> 5, pair = t & 31;
        int e = 64 * q + 2 * pair;
        const float* hp = h0 + (size_t)(bg * DB + batch) * H_DEC + e;
        unsigned v = packu(hp[0], hp[1]);
        __hip_atomic_store(&hx[(size_t)(bg * DB + batch) * 128 + 32 * q + pair], v,
                           __ATOMIC_RELAXED, __HIP_MEMORY_SCOPE_AGENT);
    }
    __syncthreads();
    if (t == 0) {
        __hip_atomic_fetch_add(&mycnt[0], 1, __ATOMIC_RELEASE, __HIP_MEMORY_SCOPE_AGENT);
        while (__hip_atomic_load(&mycnt[0], __ATOMIC_RELAXED, __HIP_MEMORY_SCOPE_AGENT) < 4) {}
    }
    __syncthreads();

    for (int s = 1; s <= T_DEC; ++s) {
        const int rb = (s - 1) & 1, wb = s & 1;
        #pragma unroll
        for (int i = 0; i < 4; ++i) {
            int j = t + 512 * i;
            int batch = j >> 7, within = j & 127;
            unsigned v = __hip_atomic_load(
                &hx[(size_t)rb * (B_TOT * 128) + (size_t)(bg * DB + batch) * 128 + within],
                __ATOMIC_RELAXED, __HIP_MEMORY_SCOPE_AGENT);
            hlU[batch][within] = v;
        }
        __syncthreads();

        {
            int batch = t >> 5, seg = t & 31;
            half8 hv = *reinterpret_cast<const half8*>(
                reinterpret_cast<const char*>(hlU) + batch * 528 + seg * 16);
            float sum = 0.f;
            #pragma unroll
            for (int j = 0; j < 8; ++j) sum += (float)hv[j] * owl[8 * seg + j];
            #pragma unroll
            for (int m = 1; m < 32; m <<= 1) sum += __shfl_xor(sum, m);
            if (seg == 0) {
                float yv = sum + ob;
                yl[batch] = (s == 1) ? 0.f : yv;
                if (q == 0 && s >= 2) out[(size_t)(bg * DB + batch) * T_DEC + (s - 2)] = yv;
            }
        }

        half8 a[8];
        #pragma unroll
        for (int kt = 0; kt < 8; ++kt)
            a[kt] = *reinterpret_cast<const half8*>(
                reinterpret_cast<const char*>(hlU) + col * 528 + (32 * kt + 8 * grp) * 2);

        f32x4 accA = {0.f, 0.f, 0.f, 0.f};
        f32x4 accB = {0.f, 0.f, 0.f, 0.f};
        #pragma unroll
        for (int kt = 0; kt < 8; ++kt) {
            accA = MFMA16(a[kt], wfA[kt], accA);
            accB = MFMA16(a[kt], wfB[kt], accB);
        }

        if (fo) {
            #pragma unroll
            for (int r = 0; r < 4; ++r) {
                exch[u][0][4 * grp + r][col] = accA[r] + bF;
                exch[u][1][4 * grp + r][col] = accB[r] + bO;
            }
        }
        __syncthreads();

        if (!fo) {
            #pragma unroll
            for (int r = 0; r < 4; ++r) {
                float yb = yl[4 * grp + r];
                float gi = sigmoidf_(accA[r] + bI + wI * yb);
                float gg = tanhf_  (accB[r] + bG + wG * yb);
                float gf = sigmoidf_(exch[u][0][4 * grp + r][col] + wF * yb);
                float go = sigmoidf_(exch[u][1][4 * grp + r][col] + wO * yb);
                c[r] = gf * c[r] + gi * gg;
                float h = go * tanhf_(c[r]);
                reinterpret_cast<_Float16*>(hnewU)[(4 * grp + r) * 64 + 16 * u + col] = (_Float16)h;
            }
        }
        __syncthreads();

        {
            int batch = t >> 5, pair = t & 31;
            __hip_atomic_store(
                &hx[(size_t)wb * (B_TOT * 128) + (size_t)(bg * DB + batch) * 128 + 32 * q + pair],
                hnewU[batch][pair], __ATOMIC_RELAXED, __HIP_MEMORY_SCOPE_AGENT);
        }
        __syncthreads();
        if (t == 0) {
            __hip_atomic_fetch_add(&mycnt[s], 1, __ATOMIC_RELEASE, __HIP_MEMORY_SCOPE_AGENT);
            while (__hip_atomic_load(&mycnt[s], __ATOMIC_RELAXED, __HIP_MEMORY_SCOPE_AGENT) < 4) {}
        }
        __syncthreads();
    }

    {
        #pragma unroll
        for (int i = 0; i < 4; ++i) {
            int j = t + 512 * i;
            int batch = j >> 7, within = j & 127;
            unsigned v = __hip_atomic_load(
                &hx[(size_t)(bg * DB + batch) * 128 + within],
                __ATOMIC_RELAXED, __HIP_MEMORY_SCOPE_AGENT);
            hlU[batch][within] = v;
        }
        __syncthreads();
        int batch = t >> 5, seg = t & 31;
        half8 hv = *reinterpret_cast<const half8*>(
            reinterpret_cast<const char*>(hlU) + batch * 528 + seg * 16);
        float sum = 0.f;
        #pragma unroll
        for (int j = 0; j < 8; ++j) sum += (float)hv[j] * owl[8 * seg + j];
        #pragma unroll
        for (int m = 1; m < 32; m <<= 1) sum += __shfl_xor(sum, m);
        if (q == 0 && seg == 0)
            out[(size_t)(bg * DB + batch) * T_DEC + (T_DEC - 1)] = sum + ob;
    }
}

extern "C" void kernel_launch(void* const* d_in, const int* in_sizes, int n_in,
                              void* d_out, int out_size, void* d_ws, size_t ws_size,
                              hipStream_t stream) {
    const float* source = (const float*)d_in[0];
    const float* eWih_f = (const float*)d_in[2];
    const float* eWhh_f = (const float*)d_in[3];
    const float* eb_f   = (const float*)d_in[4];
    const float* eWih_b = (const float*)d_in[5];
    const float* eWhh_b = (const float*)d_in[6];
    const float* eb_b   = (const float*)d_in[7];
    const float* dWih   = (const float*)d_in[8];
    const float* dWhh   = (const float*)d_in[9];
    const float* db     = (const float*)d_in[10];
    const float* oW     = (const float*)d_in[11];
    const float* obp    = (const float*)d_in[12];
    float* out = (float*)d_out;

    float*    h0  = (float*)d_ws;                       // 1 MB
    float*    c0  = h0 + (size_t)B_TOT * H_DEC;         // 1 MB
    unsigned* hx  = (unsigned*)(c0 + (size_t)B_TOT * H_DEC);  // 1 MB
    int*      cnt = (int*)(hx + (size_t)2 * B_TOT * 128);     // 64*104 ints

    zero_cnt<<<(64 * CNT_STRIDE + 255) / 256, 256, 0, stream>>>(cnt);
    encoder_big<<<128 * 2, 1024, 0, stream>>>(
        source, eWih_f, eWhh_f, eb_f, eWih_b, eWhh_b, eb_b, h0, c0);
    decoder_split<<<256, 512, 0, stream>>>(
        dWih, db, oW, obp, h0, c0, dWhh, hx, cnt, out);
}